// Round 5
// baseline (59.191 us; speedup 1.0000x reference)
//
#include <hip/hip_runtime.h>
#include <math.h>

#define NB 4
#define NS 8192
#define ND 2048
#define NK 4096   // int(0.5 * NS)

#define MV_BLOCKS   2048
#define MV_THREADS  256
#define MV_WAVES    (MV_BLOCKS * MV_THREADS / 64)      // 8192
#define TOK_PER_WAVE ((NB * NS) / MV_WAVES)            // 4

typedef float f32x4 __attribute__((ext_vector_type(4)));

// ---------------- Kernel 1: matvec + sigmoid (wave-per-token) ----------------
// w cached in 8x float4 registers per lane; per token 8 coalesced float4 loads,
// 6-shfl reduce, lane0 stores. (Identical to R4 — attribution control.)
__global__ void __launch_bounds__(MV_THREADS)
router_matvec(const float* __restrict__ hidden,
              const float* __restrict__ w,
              const float* __restrict__ bias,
              float* __restrict__ probs)
{
    const int t    = threadIdx.x;
    const int wid  = t >> 6;
    const int lane = t & 63;
    const int wave = blockIdx.x * (MV_THREADS / 64) + wid;   // 0..MV_WAVES-1

    f32x4 wreg[8];
#pragma unroll
    for (int j = 0; j < 8; ++j)
        wreg[j] = *reinterpret_cast<const f32x4*>(w + (j * 64 + lane) * 4);

    const float b0 = bias[0];

#pragma unroll
    for (int it = 0; it < TOK_PER_WAVE; ++it) {
        const int token = wave + it * MV_WAVES;
        const float* hp = hidden + (size_t)token * ND;

        float acc = 0.0f;
#pragma unroll
        for (int j = 0; j < 8; ++j) {
            const f32x4 h = *reinterpret_cast<const f32x4*>(hp + (j * 64 + lane) * 4);
            acc += h.x * wreg[j].x + h.y * wreg[j].y
                 + h.z * wreg[j].z + h.w * wreg[j].w;
        }

#pragma unroll
        for (int off = 32; off; off >>= 1) acc += __shfl_down(acc, off, 64);

        if (lane == 0)
            probs[token] = 1.0f / (1.0f + expf(-(acc + b0)));
    }
}

// ---------------- Kernel 2: per-row top-k mask + aux loss ----------------
// 1024 threads per batch row; 4-pass 8-bit histogram radix select with
// PER-WAVE padded histogram copies (hist[16][257]) to kill LDS atomic
// contention — sigmoid probs cluster heavily in 1-2 exponent bins.

__device__ __forceinline__ float block_reduce_float(float v, float* lds)
{
#pragma unroll
    for (int off = 32; off; off >>= 1) v += __shfl_down(v, off, 64);
    const int wid = threadIdx.x >> 6, lane = threadIdx.x & 63;
    __syncthreads();
    if (lane == 0) lds[wid] = v;
    __syncthreads();
    float s = 0.0f;
#pragma unroll
    for (int i = 0; i < 16; ++i) s += lds[i];
    return s;
}

__global__ void __launch_bounds__(1024)
topk_mask(const float* __restrict__ probs,
          float* __restrict__ mask,
          float* __restrict__ aux)
{
    const int b = blockIdx.x;
    const float* row = probs + b * NS;
    float*      mrow = mask  + b * NS;

    const int t = threadIdx.x;
    const int base = t * 8;
    const int wid = t >> 6, lane = t & 63;

    __shared__ int      hist[16][257];   // per-wave copies, +1 pad (bank-spread)
    __shared__ float    flds[16];
    __shared__ unsigned sbc[2];          // [0]=prefix, [1]=remaining

    float    v[8];
    unsigned u[8];
#pragma unroll
    for (int i = 0; i < 8; ++i) {
        v[i] = row[base + i];
        u[i] = __float_as_uint(v[i]);   // sigmoid > 0 => uint order == float order
    }

    // ---- row sum (deterministic) for aux loss ----
    float s = 0.0f;
#pragma unroll
    for (int i = 0; i < 8; ++i) s += v[i];
    const float rowsum = block_reduce_float(s, flds);

    // ---- 4-pass MSB radix select for the NK-th largest bit pattern ----
    int* const histf = &hist[0][0];
    unsigned prefix = 0;      // resolved high bits
    int remaining = NK;       // rank still needed inside the prefix group
#pragma unroll 1
    for (int pass = 0; pass < 4; ++pass) {
        const int shift = 24 - 8 * pass;
        for (int i = t; i < 16 * 257; i += 1024) histf[i] = 0;
        __syncthreads();

        const unsigned pmask = (pass == 0) ? 0u : (0xFFFFFFFFu << (shift + 8));
#pragma unroll
        for (int i = 0; i < 8; ++i)
            if ((u[i] & pmask) == prefix)
                atomicAdd(&hist[wid][(u[i] >> shift) & 0xFF], 1);
        __syncthreads();

        if (wid == 0) {
            // lane owns bins 4*lane .. 4*lane+3; sum the 16 wave copies
            int cnt[4];
#pragma unroll
            for (int j = 0; j < 4; ++j) {
                int c = 0;
#pragma unroll
                for (int wv = 0; wv < 16; ++wv) c += hist[wv][lane * 4 + j];
                cnt[j] = c;
            }
            const int mysum = cnt[0] + cnt[1] + cnt[2] + cnt[3];

            // reverse inclusive scan: inc = sum over lanes >= lane
            int inc = mysum;
#pragma unroll
            for (int off = 1; off < 64; off <<= 1) {
                const int y = __shfl_down(inc, off, 64);
                if (lane + off < 64) inc += y;
            }
            const int tailT = inc - mysum;   // count strictly above this lane's bins

            // local candidate: max bin d (scan j descending) with T[d] >= remaining
            int best = -1, subT = 0, Tj = tailT;
#pragma unroll
            for (int j = 3; j >= 0; --j) {
                const int Tnew = Tj + cnt[j];          // T[4*lane+j]
                if (best < 0 && Tnew >= (int)remaining) { best = lane * 4 + j; subT = Tj; }
                Tj = Tnew;
            }

            // wave max-reduce on best, carrying subT (= count strictly above best)
#pragma unroll
            for (int off = 32; off; off >>= 1) {
                const int ob = __shfl_down(best, off, 64);
                const int os = __shfl_down(subT, off, 64);
                if (ob > best) { best = ob; subT = os; }
            }
            if (lane == 0) {
                sbc[0] = prefix | ((unsigned)best << shift);
                sbc[1] = (unsigned)(remaining - subT);
            }
        }
        __syncthreads();
        prefix    = sbc[0];
        remaining = (int)sbc[1];
    }
    const unsigned thr = prefix;     // exact bits of the NK-th largest value
    const int need_ties = remaining; // # elements equal to thr to take (lowest idx first)

    // ---- exclusive scan of per-element "== thr" counts in global index order ----
    int eqc = 0;
#pragma unroll
    for (int i = 0; i < 8; ++i) eqc += (u[i] == thr) ? 1 : 0;

    int inc = eqc;                   // wave-level inclusive scan
#pragma unroll
    for (int off = 1; off < 64; off <<= 1) {
        const int y = __shfl_up(inc, off, 64);
        if (lane >= off) inc += y;
    }
    __syncthreads();
    if (lane == 63) histf[wid] = inc;
    __syncthreads();
    if (t == 0) {
        int run = 0;
#pragma unroll
        for (int wv = 0; wv < 16; ++wv) { const int x = histf[wv]; histf[wv] = run; run += x; }
    }
    __syncthreads();
    int run = (inc - eqc) + histf[wid];

    // ---- write mask ----
#pragma unroll
    for (int i = 0; i < 8; ++i) {
        float m;
        if (u[i] > thr)       m = 1.0f;
        else if (u[i] == thr) { m = (run < need_ties) ? 1.0f : 0.0f; ++run; }
        else                  m = 0.0f;
        mrow[base + i] = m;
    }

    // ---- aux loss ----
    if (t == 0) {
        const float mean = rowsum * (1.0f / (float)NS);
        const float d = mean - 0.5f;
        aux[b] = 0.01f * d * d;
    }
}

extern "C" void kernel_launch(void* const* d_in, const int* in_sizes, int n_in,
                              void* d_out, int out_size, void* d_ws, size_t ws_size,
                              hipStream_t stream)
{
    const float* hidden = (const float*)d_in[0];   // [NB, NS, ND] f32
    const float* w      = (const float*)d_in[1];   // [ND] f32
    const float* bias   = (const float*)d_in[2];   // scalar f32

    float* out   = (float*)d_out;
    float* probs = out;                 // [NB, NS]
    float* mask  = out + NB * NS;       // [NB, NS]
    float* aux   = out + 2 * NB * NS;   // [NB]

    router_matvec<<<MV_BLOCKS, MV_THREADS, 0, stream>>>(hidden, w, bias, probs);
    topk_mask<<<NB, 1024, 0, stream>>>(probs, mask, aux);
}

// Round 6
// 54.994 us; speedup vs baseline: 1.0763x; 1.0763x over previous
//
#include <hip/hip_runtime.h>
#include <math.h>

#define NB 4
#define NS 8192
#define ND 2048
#define NK 4096   // int(0.5 * NS)

// ---------------- Kernel 1: matvec + sigmoid (block-per-token, R1 shape) ----
// 256 threads per token; each thread 2x float4; low VGPR -> 32 waves/CU,
// same structural shape as the 6.3 TB/s float4-copy ubench.
__global__ void __launch_bounds__(256)
router_matvec(const float* __restrict__ hidden,
              const float* __restrict__ w,
              const float* __restrict__ bias,
              float* __restrict__ probs)
{
    const int token = blockIdx.x;                  // 0 .. NB*NS-1
    const float* hp = hidden + (size_t)token * ND;
    const int t = threadIdx.x;

    float acc = 0.0f;
#pragma unroll
    for (int j = 0; j < 2; ++j) {
        const int idx = (j * 256 + t) * 4;         // lane-contiguous float4
        const float4 h  = *reinterpret_cast<const float4*>(hp + idx);
        const float4 ww = *reinterpret_cast<const float4*>(w + idx);
        acc += h.x * ww.x + h.y * ww.y + h.z * ww.z + h.w * ww.w;
    }

    // wave (64-lane) reduce
#pragma unroll
    for (int off = 32; off; off >>= 1) acc += __shfl_down(acc, off, 64);

    __shared__ float lds[4];
    const int wid = t >> 6, lane = t & 63;
    if (lane == 0) lds[wid] = acc;
    __syncthreads();
    if (t == 0) {
        const float logit = lds[0] + lds[1] + lds[2] + lds[3] + bias[0];
        probs[token] = 1.0f / (1.0f + expf(-logit));
    }
}

// ---------------- Kernel 2: per-row top-k mask + aux loss (R4 version) -----
// 1024 threads per batch row; 4-pass 8-bit histogram radix select.

__device__ __forceinline__ float block_reduce_float(float v, float* lds)
{
#pragma unroll
    for (int off = 32; off; off >>= 1) v += __shfl_down(v, off, 64);
    const int wid = threadIdx.x >> 6, lane = threadIdx.x & 63;
    __syncthreads();
    if (lane == 0) lds[wid] = v;
    __syncthreads();
    float s = 0.0f;
#pragma unroll
    for (int i = 0; i < 16; ++i) s += lds[i];
    return s;
}

__global__ void __launch_bounds__(1024)
topk_mask(const float* __restrict__ probs,
          float* __restrict__ mask,
          float* __restrict__ aux)
{
    const int b = blockIdx.x;
    const float* row = probs + b * NS;
    float*      mrow = mask  + b * NS;

    const int t = threadIdx.x;
    const int base = t * 8;
    const int wid = t >> 6, lane = t & 63;

    __shared__ int      hist[256];
    __shared__ float    flds[16];
    __shared__ unsigned sbc[2];     // [0]=prefix, [1]=remaining

    float    v[8];
    unsigned u[8];
#pragma unroll
    for (int i = 0; i < 8; ++i) {
        v[i] = row[base + i];
        u[i] = __float_as_uint(v[i]);   // sigmoid > 0 => uint order == float order
    }

    // ---- row sum (deterministic) for aux loss ----
    float s = 0.0f;
#pragma unroll
    for (int i = 0; i < 8; ++i) s += v[i];
    const float rowsum = block_reduce_float(s, flds);

    // ---- 4-pass MSB radix select for the NK-th largest bit pattern ----
    unsigned prefix = 0;      // resolved high bits
    int remaining = NK;       // rank still needed inside the prefix group
#pragma unroll 1
    for (int pass = 0; pass < 4; ++pass) {
        const int shift = 24 - 8 * pass;
        if (t < 256) hist[t] = 0;
        __syncthreads();

        const unsigned pmask = (pass == 0) ? 0u : (0xFFFFFFFFu << (shift + 8));
#pragma unroll
        for (int i = 0; i < 8; ++i)
            if ((u[i] & pmask) == prefix)
                atomicAdd(&hist[(u[i] >> shift) & 0xFF], 1);
        __syncthreads();

        if (wid == 0) {
            // lane owns bins 4*lane .. 4*lane+3
            int cnt[4];
#pragma unroll
            for (int j = 0; j < 4; ++j) cnt[j] = hist[lane * 4 + j];
            const int mysum = cnt[0] + cnt[1] + cnt[2] + cnt[3];

            // reverse inclusive scan: inc = sum over lanes >= lane
            int inc = mysum;
#pragma unroll
            for (int off = 1; off < 64; off <<= 1) {
                const int y = __shfl_down(inc, off, 64);
                if (lane + off < 64) inc += y;
            }
            const int tailT = inc - mysum;   // count strictly above this lane's bins

            // local candidate: max bin d (scan j descending) with T[d] >= remaining
            int best = -1, subT = 0, Tj = tailT;
#pragma unroll
            for (int j = 3; j >= 0; --j) {
                const int Tnew = Tj + cnt[j];          // T[4*lane+j]
                if (best < 0 && Tnew >= (int)remaining) { best = lane * 4 + j; subT = Tj; }
                Tj = Tnew;
            }

            // wave max-reduce on best, carrying subT (= count strictly above best)
#pragma unroll
            for (int off = 32; off; off >>= 1) {
                const int ob = __shfl_down(best, off, 64);
                const int os = __shfl_down(subT, off, 64);
                if (ob > best) { best = ob; subT = os; }
            }
            if (lane == 0) {
                sbc[0] = prefix | ((unsigned)best << shift);
                sbc[1] = (unsigned)(remaining - subT);
            }
        }
        __syncthreads();
        prefix    = sbc[0];
        remaining = (int)sbc[1];
    }
    const unsigned thr = prefix;     // exact bits of the NK-th largest value
    const int need_ties = remaining; // # elements equal to thr to take (lowest idx first)

    // ---- exclusive scan of per-element "== thr" counts in global index order ----
    int eqc = 0;
#pragma unroll
    for (int i = 0; i < 8; ++i) eqc += (u[i] == thr) ? 1 : 0;

    int inc = eqc;                   // wave-level inclusive scan
#pragma unroll
    for (int off = 1; off < 64; off <<= 1) {
        const int y = __shfl_up(inc, off, 64);
        if (lane >= off) inc += y;
    }
    __syncthreads();
    if (lane == 63) hist[wid] = inc;
    __syncthreads();
    if (t == 0) {
        int run = 0;
#pragma unroll
        for (int wv = 0; wv < 16; ++wv) { const int x = hist[wv]; hist[wv] = run; run += x; }
    }
    __syncthreads();
    int run = (inc - eqc) + hist[wid];

    // ---- write mask ----
#pragma unroll
    for (int i = 0; i < 8; ++i) {
        float m;
        if (u[i] > thr)       m = 1.0f;
        else if (u[i] == thr) { m = (run < need_ties) ? 1.0f : 0.0f; ++run; }
        else                  m = 0.0f;
        mrow[base + i] = m;
    }

    // ---- aux loss ----
    if (t == 0) {
        const float mean = rowsum * (1.0f / (float)NS);
        const float d = mean - 0.5f;
        aux[b] = 0.01f * d * d;
    }
}

extern "C" void kernel_launch(void* const* d_in, const int* in_sizes, int n_in,
                              void* d_out, int out_size, void* d_ws, size_t ws_size,
                              hipStream_t stream)
{
    const float* hidden = (const float*)d_in[0];   // [NB, NS, ND] f32
    const float* w      = (const float*)d_in[1];   // [ND] f32
    const float* bias   = (const float*)d_in[2];   // scalar f32

    float* out   = (float*)d_out;
    float* probs = out;                 // [NB, NS]
    float* mask  = out + NB * NS;       // [NB, NS]
    float* aux   = out + 2 * NB * NS;   // [NB]

    router_matvec<<<NB * NS, 256, 0, stream>>>(hidden, w, bias, probs);
    topk_mask<<<NB, 1024, 0, stream>>>(probs, mask, aux);
}